// Round 4
// baseline (355.307 us; speedup 1.0000x reference)
//
#include <hip/hip_runtime.h>
#include <hip/hip_bf16.h>
#include <math.h>

#define B_ 2
#define L_ 2048
#define D_ 1024
#define N_ 16
#define CCH 64   // chunks over L
#define TCH 32   // chunk length  (CCH*TCH == L_)
#define NCOLS 1056   // D_ + 2*N_
#define NPAD  1152   // 9 * 128

typedef unsigned short u16;
typedef __attribute__((ext_vector_type(8))) short short8v;
typedef __attribute__((ext_vector_type(8))) unsigned short ushort8v;
typedef __attribute__((ext_vector_type(4))) float f32x4;

__device__ __forceinline__ float softplusf(float z) {
  return fmaxf(z, 0.f) + log1pf(__expf(-fabsf(z)));
}

__device__ __forceinline__ u16 bf16rne(float f) {
  union { float f; unsigned u; } c; c.f = f;
  unsigned u = c.u;
  u += 0x7fffu + ((u >> 16) & 1u);
  return (u16)(u >> 16);
}

__device__ __forceinline__ void gl_lds16(const void* g, const u16* lds_base,
                                         int byte_off) {
  byte_off = __builtin_amdgcn_readfirstlane(byte_off);
  __builtin_amdgcn_global_load_lds(
      (const __attribute__((address_space(1))) void*)g,
      (__attribute__((address_space(3))) void*)((const char*)lds_base + byte_off),
      16, 0, 0);
}

// ------------- K1: fused gc partial-sum + x -> bf16 pack ---------------------
// 512 blocks: (b, lc) each handles 8 rows; thread covers d-range [tid*4, +4).
__global__ __launch_bounds__(256) void k_gc_pack(const float* __restrict__ x,
    float* __restrict__ part1, u16* __restrict__ xb) {
  int blk = blockIdx.x;
  int b = blk >> 8, lc = blk & 255;
  int tid = threadIdx.x;
  int r0 = b * L_ + lc * 8;
  float4 s = {0.f, 0.f, 0.f, 0.f};
  #pragma unroll
  for (int q = 0; q < 8; ++q) {
    size_t off = (size_t)(r0 + q) * D_ + tid * 4;
    float4 v = *(const float4*)(x + off);
    s.x += v.x; s.y += v.y; s.z += v.z; s.w += v.w;
    ushort4 r;
    r.x = bf16rne(v.x); r.y = bf16rne(v.y);
    r.z = bf16rne(v.z); r.w = bf16rne(v.w);
    *(ushort4*)(xb + off) = r;
  }
  *(float4*)(part1 + (size_t)blk * D_ + tid * 4) = s;
}

// ------------- K1b: reduce part1[512][1024] -> part2[2][16][1024] ------------
__global__ __launch_bounds__(256) void k_gc_red(const float* __restrict__ part1,
                                                float* __restrict__ part2) {
  int gid = blockIdx.x * 256 + threadIdx.x;   // 32768 = (b, jc, d)
  int d = gid & 1023;
  int jc = (gid >> 10) & 15;
  int b = gid >> 14;
  float s = 0.f;
  #pragma unroll
  for (int t = 0; t < 16; ++t)
    s += part1[(size_t)(b * 256 + jc * 16 + t) * D_ + d];
  part2[gid] = s;
}

// ------------- K2: gc -> liquid scaler -> new_h [B,N] ------------------------
__global__ __launch_bounds__(256) void k_newh(const float* __restrict__ part2,
    const float* __restrict__ Wi_W, const float* __restrict__ Wi_b,
    const float* __restrict__ Wr_W, const float* __restrict__ tau,
    const float* __restrict__ h0, float* __restrict__ newh) {
  __shared__ float gcs[B_ * D_];
  int tid = threadIdx.x;
  for (int idx = tid; idx < B_ * D_; idx += 256) {
    int b = idx >> 10, d = idx & (D_ - 1);
    float s = 0.f;
    #pragma unroll
    for (int lc = 0; lc < 16; ++lc)
      s += part2[(size_t)((b << 4) | lc) * D_ + d];
    gcs[idx] = s * (1.f / L_);
  }
  __syncthreads();
  if (tid < B_ * N_) {
    int b = tid >> 4, n = tid & 15;
    float inp = Wi_b[n];
    const float* g = gcs + b * D_;
    const float* w = Wi_W + n * D_;
    for (int d = 0; d < D_; d += 4) {
      float4 gv = *(const float4*)(g + d);
      float4 wv = *(const float4*)(w + d);
      inp += gv.x * wv.x + gv.y * wv.y + gv.z * wv.z + gv.w * wv.w;
    }
    float rec = 0.f;
    for (int m = 0; m < N_; ++m) rec += h0[m] * Wr_W[n * N_ + m];
    float th = tanhf(inp + rec);
    float tc = fminf(fmaxf(tau[n], 0.1f), 10.f);
    float cur = h0[n];
    newh[tid] = cur + 0.1f * ((th - cur) / tc);   // DT = 0.1
  }
}

// ------------- K3: sel[b,d] = sigmoid(new_h @ sel_W.T + sel_b) ---------------
__global__ __launch_bounds__(256) void k_sel(const float* __restrict__ newh,
    const float* __restrict__ sel_W, const float* __restrict__ sel_b,
    float* __restrict__ sel) {
  int gid = blockIdx.x * 256 + threadIdx.x;   // over B*D
  int b = gid >> 10, d = gid & (D_ - 1);
  const float* w = sel_W + d * N_;
  const float* h = newh + b * N_;
  float z = sel_b[d];
  #pragma unroll
  for (int n = 0; n < N_; n += 4) {
    float4 wv = *(const float4*)(w + n);
    z += h[n] * wv.x + h[n + 1] * wv.y + h[n + 2] * wv.z + h[n + 3] * wv.w;
  }
  sel[gid] = 1.f / (1.f + __expf(-z));
}

// ------------- K4: pack [delta_W; B_W; C_W] * sel(b) -> bf16 -----------------
__global__ __launch_bounds__(256) void k_pack_w(const float* __restrict__ dW,
    const float* __restrict__ B_W, const float* __restrict__ C_W,
    const float* __restrict__ sel, u16* __restrict__ Wp) {
  int gid = blockIdx.x * 256 + threadIdx.x;    // 147456 threads, 8 elems each
  int b = blockIdx.y;
  size_t e = (size_t)gid * 8;                  // < 1179648
  int nn = (int)(e >> 10);
  int k = (int)(e & 1023);
  ushort8v r;
  if (nn < NCOLS) {
    const float* src = (nn < 1024) ? dW + (size_t)nn * 1024
                     : (nn < 1040) ? B_W + (size_t)(nn - 1024) * 1024
                                   : C_W + (size_t)(nn - 1040) * 1024;
    float4 s0 = *(const float4*)(src + k);
    float4 s1 = *(const float4*)(src + k + 4);
    const float* sp = sel + b * D_ + k;
    float4 e0 = *(const float4*)sp;
    float4 e1 = *(const float4*)(sp + 4);
    r[0] = bf16rne(s0.x * e0.x); r[1] = bf16rne(s0.y * e0.y);
    r[2] = bf16rne(s0.z * e0.z); r[3] = bf16rne(s0.w * e0.w);
    r[4] = bf16rne(s1.x * e1.x); r[5] = bf16rne(s1.y * e1.y);
    r[6] = bf16rne(s1.z * e1.z); r[7] = bf16rne(s1.w * e1.w);
  } else {
    r = (ushort8v)0;
  }
  *(ushort8v*)(Wp + (size_t)b * (NPAD * 1024) + e) = r;
}

// ------------- K5: MFMA GEMM  C[4096 x 1152] = xb @ Wp^T ---------------------
// 128x128 tile, BK=64, 4 waves (2x2, wave-tile 64x64), double-buffered
// global_load_lds with counted vmcnt(8) (loads in flight across barriers),
// XOR-swizzled source + swizzled ds_read (rule #21).
__global__ __launch_bounds__(256) void k_gemm(
    const u16* __restrict__ xb, const u16* __restrict__ Wp,
    const float* __restrict__ delta_b, const float* __restrict__ dt_bias,
    const float* __restrict__ B_b, const float* __restrict__ C_b,
    float* __restrict__ delta, float* __restrict__ Bm, float* __restrict__ Cm) {
  __shared__ __align__(16) u16 lds[4][8192];   // At0,At1,Bt0,Bt1 (16 KB each)
  int m0 = blockIdx.x * 128;
  int n0 = blockIdx.y * 128;
  int batch = blockIdx.x >> 4;                 // 16 m-tiles per batch
  const u16* wb = Wp + (size_t)batch * (NPAD * 1024);
  int tid = threadIdx.x;
  int w = tid >> 6, l = tid & 63;
  int wr = w >> 1, wc = w & 1;
  int srow = l >> 3;                           // row within 8-group == row&7
  int ssl = (l & 7) ^ srow;                    // swizzled logical 16B slot

  f32x4 acc[4][4];
  #pragma unroll
  for (int m = 0; m < 4; ++m)
    #pragma unroll
    for (int n = 0; n < 4; ++n)
      acc[m][n] = (f32x4){0.f, 0.f, 0.f, 0.f};

  // wave w stages rows [w*32, w*32+32) of both A and B: 8 gl_lds per wave.
  #define STAGE(kb, buf)                                                       \
    {                                                                          \
      _Pragma("unroll")                                                        \
      for (int q = 0; q < 4; ++q) {                                            \
        int row = w * 32 + q * 8 + srow;                                       \
        gl_lds16(xb + (size_t)(m0 + row) * 1024 + (kb) * 64 + ssl * 8,         \
                 &lds[0][0], (buf) * 16384 + (w * 32 + q * 8) * 128);          \
        gl_lds16(wb + (size_t)(n0 + row) * 1024 + (kb) * 64 + ssl * 8,         \
                 &lds[0][0], 32768 + (buf) * 16384 + (w * 32 + q * 8) * 128);  \
      }                                                                        \
    }

  int lr = l & 15, lh = l >> 4;                // lh 0..3

  #define CSTEP(cur)                                                           \
    {                                                                          \
      _Pragma("unroll")                                                        \
      for (int ks = 0; ks < 2; ++ks) {                                         \
        short8v a[4], bq[4];                                                   \
        _Pragma("unroll")                                                      \
        for (int m = 0; m < 4; ++m) {                                          \
          int r = wr * 64 + m * 16 + lr;                                       \
          int ps = (ks * 4 + lh) ^ (r & 7);                                    \
          a[m] = *(const short8v*)((const char*)&lds[cur][0] + r * 128 + ps * 16);\
        }                                                                      \
        _Pragma("unroll")                                                      \
        for (int n = 0; n < 4; ++n) {                                          \
          int r = wc * 64 + n * 16 + lr;                                       \
          int ps = (ks * 4 + lh) ^ (r & 7);                                    \
          bq[n] = *(const short8v*)((const char*)&lds[2 + (cur)][0] + r * 128 + ps * 16);\
        }                                                                      \
        _Pragma("unroll")                                                      \
        for (int m = 0; m < 4; ++m)                                            \
          _Pragma("unroll")                                                    \
          for (int n = 0; n < 4; ++n)                                          \
            acc[m][n] = __builtin_amdgcn_mfma_f32_16x16x32_bf16(a[m], bq[n],   \
                                                                acc[m][n], 0, 0, 0);\
      }                                                                        \
    }

  STAGE(0, 0);
  STAGE(1, 1);
  #pragma unroll
  for (int kb = 0; kb < 15; ++kb) {
    int cur = kb & 1;
    asm volatile("s_waitcnt vmcnt(8)" ::: "memory");   // tile kb staged
    __builtin_amdgcn_s_barrier();
    CSTEP(cur);
    asm volatile("s_waitcnt lgkmcnt(0)" ::: "memory"); // my reads of buf done
    __builtin_amdgcn_s_barrier();                      // everyone's reads done
    if (kb < 14) STAGE(kb + 2, cur);
  }
  asm volatile("s_waitcnt vmcnt(0)" ::: "memory");
  __builtin_amdgcn_s_barrier();
  CSTEP(1);
  #undef STAGE
  #undef CSTEP

  int ibase = m0 + wr * 64 + lh * 4;
  int jbase = n0 + wc * 64 + lr;
  #pragma unroll
  for (int m = 0; m < 4; ++m) {
    #pragma unroll
    for (int n = 0; n < 4; ++n) {
      int j = jbase + n * 16;
      #pragma unroll
      for (int r = 0; r < 4; ++r) {
        int i = ibase + m * 16 + r;
        float v = acc[m][n][r];
        if (j < 1024) {
          delta[(size_t)i * D_ + j] = softplusf(v + delta_b[j] + dt_bias[j]);
        } else if (j < 1040) {
          Bm[i * N_ + (j - 1024)] = v + B_b[j - 1024];
        } else if (j < NCOLS) {
          Cm[i * N_ + (j - 1040)] = v + C_b[j - 1040];
        }
      }
    }
  }
}

// ------------- K6: scan pass 1 — local scan + decay product ------------------
// Register burst-preload of x/delta (one latency instead of 32), full unroll.
__global__ __launch_bounds__(256) void k_scan1(const float* __restrict__ x,
    const float* __restrict__ sel, const float* __restrict__ delta,
    const float* __restrict__ Bm, const float* __restrict__ A_log,
    float* __restrict__ prodA, float* __restrict__ hend) {
  int gid = blockIdx.x * 256 + threadIdx.x;   // (b*CCH + c)*D_ + d
  int d = gid & (D_ - 1);
  int b = gid >> 16;
  int c = (gid >> 10) & (CCH - 1);
  int row0 = b * L_ + c * TCH;
  const float* xp = x + (size_t)row0 * D_ + d;
  const float* dp = delta + (size_t)row0 * D_ + d;
  float xr[TCH], dl[TCH];
  #pragma unroll
  for (int s = 0; s < TCH; ++s) {
    xr[s] = xp[(size_t)s * D_];
    dl[s] = dp[(size_t)s * D_];
  }
  float A[N_], rA[N_];
  unsigned smallm = 0;
  #pragma unroll
  for (int n = 0; n < N_; ++n) {
    float a = -__expf(A_log[d * N_ + n]);
    A[n] = a;
    rA[n] = 1.f / a;
    if (fabsf(a) < 1e-6f) smallm |= (1u << n);
  }
  float selv = sel[b * D_ + d];
  float h[N_], p[N_];
  #pragma unroll
  for (int n = 0; n < N_; ++n) { h[n] = 0.f; p[n] = 1.f; }
  #pragma unroll
  for (int s = 0; s < TCH; ++s) {
    int row = row0 + s;
    float dlt = dl[s];
    float xv = xr[s] * selv;
    const float4* bmp = (const float4*)(Bm + (size_t)row * N_);
    float4 q0 = bmp[0], q1 = bmp[1], q2 = bmp[2], q3 = bmp[3];
    float bmv[N_] = {q0.x,q0.y,q0.z,q0.w, q1.x,q1.y,q1.z,q1.w,
                     q2.x,q2.y,q2.z,q2.w, q3.x,q3.y,q3.z,q3.w};
    #pragma unroll
    for (int n = 0; n < N_; ++n) {
      float Ad = __expf(A[n] * dlt);
      float f = ((smallm >> n) & 1u) ? dlt : (Ad - 1.f) * rA[n];
      h[n] = Ad * h[n] + (f * bmv[n]) * xv;
      p[n] *= Ad;
    }
  }
  float4* pp = (float4*)(prodA + (size_t)gid * N_);
  float4* hp = (float4*)(hend + (size_t)gid * N_);
  pp[0] = make_float4(p[0], p[1], p[2], p[3]);
  pp[1] = make_float4(p[4], p[5], p[6], p[7]);
  pp[2] = make_float4(p[8], p[9], p[10], p[11]);
  pp[3] = make_float4(p[12], p[13], p[14], p[15]);
  hp[0] = make_float4(h[0], h[1], h[2], h[3]);
  hp[1] = make_float4(h[4], h[5], h[6], h[7]);
  hp[2] = make_float4(h[8], h[9], h[10], h[11]);
  hp[3] = make_float4(h[12], h[13], h[14], h[15]);
}

// ------------- K7: scan pass 2 — cross-chunk prefix (per b,d,n) --------------
// 64 steps in 4 burst-prefetched groups of 16.
__global__ __launch_bounds__(256) void k_scan2(const float* __restrict__ prodA,
    const float* __restrict__ hend, float* __restrict__ hin) {
  int gid = blockIdx.x * 256 + threadIdx.x;   // over B*D*N = 32768
  int b = gid >> 14;
  int rem = gid & 16383;
  size_t base = ((size_t)(b * CCH) << 14) + rem;
  float H = 0.f;
  #pragma unroll
  for (int g = 0; g < 4; ++g) {
    float pg[16], hg[16];
    #pragma unroll
    for (int t = 0; t < 16; ++t) {
      size_t idx = base + ((size_t)(g * 16 + t) << 14);
      pg[t] = prodA[idx];
      hg[t] = hend[idx];
    }
    #pragma unroll
    for (int t = 0; t < 16; ++t) {
      size_t idx = base + ((size_t)(g * 16 + t) << 14);
      hin[idx] = H;
      H = pg[t] * H + hg[t];
    }
  }
}

// ------------- K8: scan pass 3 — re-scan with carry-in, emit y ---------------
__global__ __launch_bounds__(256) void k_scan3(const float* __restrict__ x,
    const float* __restrict__ sel, const float* __restrict__ delta,
    const float* __restrict__ Bm, const float* __restrict__ Cm,
    const float* __restrict__ A_log, const float* __restrict__ hin,
    float* __restrict__ out) {
  int gid = blockIdx.x * 256 + threadIdx.x;
  int d = gid & (D_ - 1);
  int b = gid >> 16;
  int c = (gid >> 10) & (CCH - 1);
  int row0 = b * L_ + c * TCH;
  const float* xp = x + (size_t)row0 * D_ + d;
  const float* dp = delta + (size_t)row0 * D_ + d;
  float xr[TCH], dl[TCH];
  #pragma unroll
  for (int s = 0; s < TCH; ++s) {
    xr[s] = xp[(size_t)s * D_];
    dl[s] = dp[(size_t)s * D_];
  }
  float A[N_], rA[N_];
  unsigned smallm = 0;
  #pragma unroll
  for (int n = 0; n < N_; ++n) {
    float a = -__expf(A_log[d * N_ + n]);
    A[n] = a;
    rA[n] = 1.f / a;
    if (fabsf(a) < 1e-6f) smallm |= (1u << n);
  }
  float selv = sel[b * D_ + d];
  float h[N_];
  {
    const float4* hp = (const float4*)(hin + (size_t)gid * N_);
    float4 v0 = hp[0], v1 = hp[1], v2 = hp[2], v3 = hp[3];
    h[0]=v0.x; h[1]=v0.y; h[2]=v0.z; h[3]=v0.w;
    h[4]=v1.x; h[5]=v1.y; h[6]=v1.z; h[7]=v1.w;
    h[8]=v2.x; h[9]=v2.y; h[10]=v2.z; h[11]=v2.w;
    h[12]=v3.x; h[13]=v3.y; h[14]=v3.z; h[15]=v3.w;
  }
  #pragma unroll
  for (int s = 0; s < TCH; ++s) {
    int row = row0 + s;
    size_t idx = (size_t)row * D_ + d;
    float dlt = dl[s];
    float xv = xr[s] * selv;
    const float4* bmp = (const float4*)(Bm + (size_t)row * N_);
    float4 q0 = bmp[0], q1 = bmp[1], q2 = bmp[2], q3 = bmp[3];
    float bmv[N_] = {q0.x,q0.y,q0.z,q0.w, q1.x,q1.y,q1.z,q1.w,
                     q2.x,q2.y,q2.z,q2.w, q3.x,q3.y,q3.z,q3.w};
    const float4* cmp = (const float4*)(Cm + (size_t)row * N_);
    float4 r0 = cmp[0], r1 = cmp[1], r2 = cmp[2], r3 = cmp[3];
    float cmv[N_] = {r0.x,r0.y,r0.z,r0.w, r1.x,r1.y,r1.z,r1.w,
                     r2.x,r2.y,r2.z,r2.w, r3.x,r3.y,r3.z,r3.w};
    float y = 0.f;
    #pragma unroll
    for (int n = 0; n < N_; ++n) {
      float Ad = __expf(A[n] * dlt);
      float f = ((smallm >> n) & 1u) ? dlt : (Ad - 1.f) * rA[n];
      h[n] = Ad * h[n] + (f * bmv[n]) * xv;
      y += h[n] * cmv[n];
    }
    out[idx] = y;
  }
}

extern "C" void kernel_launch(void* const* d_in, const int* in_sizes, int n_in,
                              void* d_out, int out_size, void* d_ws, size_t ws_size,
                              hipStream_t stream) {
  const float* x       = (const float*)d_in[0];
  const float* deltaW  = (const float*)d_in[1];
  const float* deltab  = (const float*)d_in[2];
  const float* B_W     = (const float*)d_in[3];
  const float* B_b     = (const float*)d_in[4];
  const float* C_W     = (const float*)d_in[5];
  const float* C_b     = (const float*)d_in[6];
  const float* A_log   = (const float*)d_in[7];
  const float* dt_bias = (const float*)d_in[8];
  const float* tau     = (const float*)d_in[9];
  const float* Wi_W    = (const float*)d_in[10];
  const float* Wi_b    = (const float*)d_in[11];
  const float* Wr_W    = (const float*)d_in[12];
  const float* sel_W   = (const float*)d_in[13];
  const float* sel_b   = (const float*)d_in[14];
  const float* h0      = (const float*)d_in[15];
  float* out = (float*)d_out;

  float* ws    = (float*)d_ws;          // ~42.9 MB total
  float* delta = ws;                    // 4,194,304
  float* newh  = delta + 4194304;       // 64
  float* selp  = newh + 64;             // 2,048
  float* Bm    = selp + 2048;           // 65,536
  float* Cm    = Bm + 65536;            // 65,536
  float* prodA = Cm + 65536;            // 2,097,152  (aliases xb)
  float* hend  = prodA + 2097152;       // 2,097,152  (aliases Wp)
  float* hin   = hend + 2097152;        // 2,097,152  (aliases part1/part2)
  u16* xb    = (u16*)prodA;             // 4096*1024 bf16 (8 MB), dead before scan1
  u16* Wp    = (u16*)hend;              // 2*1152*1024 bf16 (4.7 MB), dead before scan1
  float* part1 = hin;                   // 524,288 — dead before scan2
  float* part2 = hin + 524288;          // 32,768  — dead before scan2

  hipLaunchKernelGGL(k_gc_pack, dim3(512), dim3(256), 0, stream, x, part1, xb);
  hipLaunchKernelGGL(k_gc_red, dim3(128), dim3(256), 0, stream, part1, part2);
  hipLaunchKernelGGL(k_newh, dim3(1), dim3(256), 0, stream,
                     part2, Wi_W, Wi_b, Wr_W, tau, h0, newh);
  hipLaunchKernelGGL(k_sel, dim3(8), dim3(256), 0, stream,
                     newh, sel_W, sel_b, selp);
  hipLaunchKernelGGL(k_pack_w, dim3(576, 2), dim3(256), 0, stream,
                     deltaW, B_W, C_W, selp, Wp);
  hipLaunchKernelGGL(k_gemm, dim3(32, 9), dim3(256), 0, stream,
                     xb, Wp, deltab, dt_bias, B_b, C_b, delta, Bm, Cm);
  hipLaunchKernelGGL(k_scan1, dim3(512), dim3(256), 0, stream,
                     x, selp, delta, Bm, A_log, prodA, hend);
  hipLaunchKernelGGL(k_scan2, dim3(128), dim3(256), 0, stream,
                     prodA, hend, hin);
  hipLaunchKernelGGL(k_scan3, dim3(512), dim3(256), 0, stream,
                     x, selp, delta, Bm, Cm, A_log, hin, out);
}

// Round 6
// 215.321 us; speedup vs baseline: 1.6501x; 1.6501x over previous
//
#include <hip/hip_runtime.h>
#include <hip/hip_bf16.h>
#include <math.h>

#define B_ 2
#define L_ 2048
#define D_ 1024
#define N_ 16
#define CCH 64   // chunks over L
#define TCH 32   // chunk length  (CCH*TCH == L_)
#define NCOLS 1056   // D_ + 2*N_
#define NPAD  1152   // 9 * 128

typedef unsigned short u16;
typedef __attribute__((ext_vector_type(8))) short short8v;
typedef __attribute__((ext_vector_type(8))) unsigned short ushort8v;
typedef __attribute__((ext_vector_type(4))) float f32x4;

__device__ __forceinline__ float softplusf(float z) {
  return fmaxf(z, 0.f) + log1pf(__expf(-fabsf(z)));
}

__device__ __forceinline__ u16 bf16rne(float f) {
  union { float f; unsigned u; } c; c.f = f;
  unsigned u = c.u;
  u += 0x7fffu + ((u >> 16) & 1u);
  return (u16)(u >> 16);
}

__device__ __forceinline__ void gl_lds16(const void* g, const u16* lds_base,
                                         int byte_off) {
  byte_off = __builtin_amdgcn_readfirstlane(byte_off);
  __builtin_amdgcn_global_load_lds(
      (const __attribute__((address_space(1))) void*)g,
      (__attribute__((address_space(3))) void*)((const char*)lds_base + byte_off),
      16, 0, 0);
}

// ------------- K1: fused gc partial-sum + x -> bf16 pack ---------------------
__global__ __launch_bounds__(256) void k_gc_pack(const float* __restrict__ x,
    float* __restrict__ part1, u16* __restrict__ xb) {
  int blk = blockIdx.x;
  int b = blk >> 8, lc = blk & 255;
  int tid = threadIdx.x;
  int r0 = b * L_ + lc * 8;
  float4 s = {0.f, 0.f, 0.f, 0.f};
  #pragma unroll
  for (int q = 0; q < 8; ++q) {
    size_t off = (size_t)(r0 + q) * D_ + tid * 4;
    float4 v = *(const float4*)(x + off);
    s.x += v.x; s.y += v.y; s.z += v.z; s.w += v.w;
    ushort4 r;
    r.x = bf16rne(v.x); r.y = bf16rne(v.y);
    r.z = bf16rne(v.z); r.w = bf16rne(v.w);
    *(ushort4*)(xb + off) = r;
  }
  *(float4*)(part1 + (size_t)blk * D_ + tid * 4) = s;
}

// ------------- K1b: reduce part1[512][1024] -> part2[2][16][1024] ------------
__global__ __launch_bounds__(256) void k_gc_red(const float* __restrict__ part1,
                                                float* __restrict__ part2) {
  int gid = blockIdx.x * 256 + threadIdx.x;   // 32768 = (b, jc, d)
  int d = gid & 1023;
  int jc = (gid >> 10) & 15;
  int b = gid >> 14;
  float s = 0.f;
  #pragma unroll
  for (int t = 0; t < 16; ++t)
    s += part1[(size_t)(b * 256 + jc * 16 + t) * D_ + d];
  part2[gid] = s;
}

// ------------- K2: gc -> liquid scaler -> new_h [B,N] ------------------------
__global__ __launch_bounds__(256) void k_newh(const float* __restrict__ part2,
    const float* __restrict__ Wi_W, const float* __restrict__ Wi_b,
    const float* __restrict__ Wr_W, const float* __restrict__ tau,
    const float* __restrict__ h0, float* __restrict__ newh) {
  __shared__ float gcs[B_ * D_];
  int tid = threadIdx.x;
  for (int idx = tid; idx < B_ * D_; idx += 256) {
    int b = idx >> 10, d = idx & (D_ - 1);
    float s = 0.f;
    #pragma unroll
    for (int lc = 0; lc < 16; ++lc)
      s += part2[(size_t)((b << 4) | lc) * D_ + d];
    gcs[idx] = s * (1.f / L_);
  }
  __syncthreads();
  if (tid < B_ * N_) {
    int b = tid >> 4, n = tid & 15;
    float inp = Wi_b[n];
    const float* g = gcs + b * D_;
    const float* w = Wi_W + n * D_;
    for (int d = 0; d < D_; d += 4) {
      float4 gv = *(const float4*)(g + d);
      float4 wv = *(const float4*)(w + d);
      inp += gv.x * wv.x + gv.y * wv.y + gv.z * wv.z + gv.w * wv.w;
    }
    float rec = 0.f;
    for (int m = 0; m < N_; ++m) rec += h0[m] * Wr_W[n * N_ + m];
    float th = tanhf(inp + rec);
    float tc = fminf(fmaxf(tau[n], 0.1f), 10.f);
    float cur = h0[n];
    newh[tid] = cur + 0.1f * ((th - cur) / tc);   // DT = 0.1
  }
}

// ------------- K3: sel[b,d] = sigmoid(new_h @ sel_W.T + sel_b) ---------------
__global__ __launch_bounds__(256) void k_sel(const float* __restrict__ newh,
    const float* __restrict__ sel_W, const float* __restrict__ sel_b,
    float* __restrict__ sel) {
  int gid = blockIdx.x * 256 + threadIdx.x;   // over B*D
  int b = gid >> 10, d = gid & (D_ - 1);
  const float* w = sel_W + d * N_;
  const float* h = newh + b * N_;
  float z = sel_b[d];
  #pragma unroll
  for (int n = 0; n < N_; n += 4) {
    float4 wv = *(const float4*)(w + n);
    z += h[n] * wv.x + h[n + 1] * wv.y + h[n + 2] * wv.z + h[n + 3] * wv.w;
  }
  sel[gid] = 1.f / (1.f + __expf(-z));
}

// ------------- K4: pack [delta_W; B_W; C_W] * sel(b) -> bf16 -----------------
__global__ __launch_bounds__(256) void k_pack_w(const float* __restrict__ dW,
    const float* __restrict__ B_W, const float* __restrict__ C_W,
    const float* __restrict__ sel, u16* __restrict__ Wp) {
  int gid = blockIdx.x * 256 + threadIdx.x;    // 147456 threads, 8 elems each
  int b = blockIdx.y;
  size_t e = (size_t)gid * 8;                  // < 1179648
  int nn = (int)(e >> 10);
  int k = (int)(e & 1023);
  ushort8v r;
  if (nn < NCOLS) {
    const float* src = (nn < 1024) ? dW + (size_t)nn * 1024
                     : (nn < 1040) ? B_W + (size_t)(nn - 1024) * 1024
                                   : C_W + (size_t)(nn - 1040) * 1024;
    float4 s0 = *(const float4*)(src + k);
    float4 s1 = *(const float4*)(src + k + 4);
    const float* sp = sel + b * D_ + k;
    float4 e0 = *(const float4*)sp;
    float4 e1 = *(const float4*)(sp + 4);
    r[0] = bf16rne(s0.x * e0.x); r[1] = bf16rne(s0.y * e0.y);
    r[2] = bf16rne(s0.z * e0.z); r[3] = bf16rne(s0.w * e0.w);
    r[4] = bf16rne(s1.x * e1.x); r[5] = bf16rne(s1.y * e1.y);
    r[6] = bf16rne(s1.z * e1.z); r[7] = bf16rne(s1.w * e1.w);
  } else {
    r = (ushort8v)0;
  }
  *(ushort8v*)(Wp + (size_t)b * (NPAD * 1024) + e) = r;
}

// ------------- K5: MFMA GEMM  C[4096 x 1152] = xb @ Wp^T ---------------------
// 128x128 tile, BK=64, double-buffered global_load_lds, counted vmcnt(8).
__global__ __launch_bounds__(256) void k_gemm(
    const u16* __restrict__ xb, const u16* __restrict__ Wp,
    const float* __restrict__ delta_b, const float* __restrict__ dt_bias,
    const float* __restrict__ B_b, const float* __restrict__ C_b,
    float* __restrict__ delta, float* __restrict__ Bm, float* __restrict__ Cm) {
  __shared__ __align__(16) u16 lds[4][8192];   // At0,At1,Bt0,Bt1 (16 KB each)
  int m0 = blockIdx.x * 128;
  int n0 = blockIdx.y * 128;
  int batch = blockIdx.x >> 4;                 // 16 m-tiles per batch
  const u16* wb = Wp + (size_t)batch * (NPAD * 1024);
  int tid = threadIdx.x;
  int w = tid >> 6, l = tid & 63;
  int wr = w >> 1, wc = w & 1;
  int srow = l >> 3;
  int ssl = (l & 7) ^ srow;

  f32x4 acc[4][4];
  #pragma unroll
  for (int m = 0; m < 4; ++m)
    #pragma unroll
    for (int n = 0; n < 4; ++n)
      acc[m][n] = (f32x4){0.f, 0.f, 0.f, 0.f};

  #define STAGE(kb, buf)                                                       \
    {                                                                          \
      _Pragma("unroll")                                                        \
      for (int q = 0; q < 4; ++q) {                                            \
        int row = w * 32 + q * 8 + srow;                                       \
        gl_lds16(xb + (size_t)(m0 + row) * 1024 + (kb) * 64 + ssl * 8,         \
                 &lds[0][0], (buf) * 16384 + (w * 32 + q * 8) * 128);          \
        gl_lds16(wb + (size_t)(n0 + row) * 1024 + (kb) * 64 + ssl * 8,         \
                 &lds[0][0], 32768 + (buf) * 16384 + (w * 32 + q * 8) * 128);  \
      }                                                                        \
    }

  int lr = l & 15, lh = l >> 4;

  #define CSTEP(cur)                                                           \
    {                                                                          \
      _Pragma("unroll")                                                        \
      for (int ks = 0; ks < 2; ++ks) {                                         \
        short8v a[4], bq[4];                                                   \
        _Pragma("unroll")                                                      \
        for (int m = 0; m < 4; ++m) {                                          \
          int r = wr * 64 + m * 16 + lr;                                       \
          int ps = (ks * 4 + lh) ^ (r & 7);                                    \
          a[m] = *(const short8v*)((const char*)&lds[cur][0] + r * 128 + ps * 16);\
        }                                                                      \
        _Pragma("unroll")                                                      \
        for (int n = 0; n < 4; ++n) {                                          \
          int r = wc * 64 + n * 16 + lr;                                       \
          int ps = (ks * 4 + lh) ^ (r & 7);                                    \
          bq[n] = *(const short8v*)((const char*)&lds[2 + (cur)][0] + r * 128 + ps * 16);\
        }                                                                      \
        _Pragma("unroll")                                                      \
        for (int m = 0; m < 4; ++m)                                            \
          _Pragma("unroll")                                                    \
          for (int n = 0; n < 4; ++n)                                          \
            acc[m][n] = __builtin_amdgcn_mfma_f32_16x16x32_bf16(a[m], bq[n],   \
                                                                acc[m][n], 0, 0, 0);\
      }                                                                        \
    }

  STAGE(0, 0);
  STAGE(1, 1);
  #pragma unroll
  for (int kb = 0; kb < 15; ++kb) {
    int cur = kb & 1;
    asm volatile("s_waitcnt vmcnt(8)" ::: "memory");
    __builtin_amdgcn_s_barrier();
    CSTEP(cur);
    asm volatile("s_waitcnt lgkmcnt(0)" ::: "memory");
    __builtin_amdgcn_s_barrier();
    if (kb < 14) STAGE(kb + 2, cur);
  }
  asm volatile("s_waitcnt vmcnt(0)" ::: "memory");
  __builtin_amdgcn_s_barrier();
  CSTEP(1);
  #undef STAGE
  #undef CSTEP

  int ibase = m0 + wr * 64 + lh * 4;
  int jbase = n0 + wc * 64 + lr;
  #pragma unroll
  for (int m = 0; m < 4; ++m) {
    #pragma unroll
    for (int n = 0; n < 4; ++n) {
      int j = jbase + n * 16;
      #pragma unroll
      for (int r = 0; r < 4; ++r) {
        int i = ibase + m * 16 + r;
        float v = acc[m][n][r];
        if (j < 1024) {
          delta[(size_t)i * D_ + j] = softplusf(v + delta_b[j] + dt_bias[j]);
        } else if (j < 1040) {
          Bm[i * N_ + (j - 1024)] = v + B_b[j - 1024];
        } else if (j < NCOLS) {
          Cm[i * N_ + (j - 1040)] = v + C_b[j - 1040];
        }
      }
    }
  }
}

// ------------- K6: scan pass 1 — local scan + decay product ------------------
// N-split: thread = (b, c, d, nh); 8 states each; 1024 blocks (262144 threads).
__global__ __launch_bounds__(256) void k_scan1(const float* __restrict__ x,
    const float* __restrict__ sel, const float* __restrict__ delta,
    const float* __restrict__ Bm, const float* __restrict__ A_log,
    float* __restrict__ prodA, float* __restrict__ hend) {
  int gid = blockIdx.x * 256 + threadIdx.x;   // ((b*CCH+c)*D + d)*2 + nh
  int nh = gid & 1;
  int d = (gid >> 1) & (D_ - 1);
  int c = (gid >> 11) & (CCH - 1);
  int b = gid >> 17;
  float A[8], rA[8];
  unsigned smallm = 0;
  {
    const float4* ap = (const float4*)(A_log + d * N_ + nh * 8);
    float4 a0 = ap[0], a1 = ap[1];
    float av[8] = {a0.x, a0.y, a0.z, a0.w, a1.x, a1.y, a1.z, a1.w};
    #pragma unroll
    for (int n = 0; n < 8; ++n) {
      float a = -__expf(av[n]);
      A[n] = a; rA[n] = 1.f / a;
      if (fabsf(a) < 1e-6f) smallm |= (1u << n);
    }
  }
  float selv = sel[b * D_ + d];
  float h[8], p[8];
  #pragma unroll
  for (int n = 0; n < 8; ++n) { h[n] = 0.f; p[n] = 1.f; }
  int row0 = b * L_ + c * TCH;
  #pragma unroll 4
  for (int s = 0; s < TCH; ++s) {
    int row = row0 + s;
    size_t idx = (size_t)row * D_ + d;
    float dlt = delta[idx];
    float xv = x[idx] * selv;
    const float4* bmp = (const float4*)(Bm + (size_t)row * N_ + nh * 8);
    float4 q0 = bmp[0], q1 = bmp[1];
    float bmv[8] = {q0.x, q0.y, q0.z, q0.w, q1.x, q1.y, q1.z, q1.w};
    #pragma unroll
    for (int n = 0; n < 8; ++n) {
      float Ad = __expf(A[n] * dlt);
      float f = ((smallm >> n) & 1u) ? dlt : (Ad - 1.f) * rA[n];
      h[n] = Ad * h[n] + (f * bmv[n]) * xv;
      p[n] *= Ad;
    }
  }
  size_t base = ((size_t)(gid >> 1)) * N_ + nh * 8;
  float4* pp = (float4*)(prodA + base);
  float4* hp = (float4*)(hend + base);
  pp[0] = make_float4(p[0], p[1], p[2], p[3]);
  pp[1] = make_float4(p[4], p[5], p[6], p[7]);
  hp[0] = make_float4(h[0], h[1], h[2], h[3]);
  hp[1] = make_float4(h[4], h[5], h[6], h[7]);
}

// ------------- K7: scan pass 2 — cross-chunk prefix (per b,d,n) --------------
__global__ __launch_bounds__(256) void k_scan2(const float* __restrict__ prodA,
    const float* __restrict__ hend, float* __restrict__ hin) {
  int gid = blockIdx.x * 256 + threadIdx.x;   // over B*D*N = 32768
  int b = gid >> 14;
  int rem = gid & 16383;
  size_t base = ((size_t)(b * CCH) << 14) + rem;
  float H = 0.f;
  #pragma unroll
  for (int g = 0; g < 4; ++g) {
    float pg[16], hg[16];
    #pragma unroll
    for (int t = 0; t < 16; ++t) {
      size_t idx = base + ((size_t)(g * 16 + t) << 14);
      pg[t] = prodA[idx];
      hg[t] = hend[idx];
    }
    #pragma unroll
    for (int t = 0; t < 16; ++t) {
      size_t idx = base + ((size_t)(g * 16 + t) << 14);
      hin[idx] = H;
      H = pg[t] * H + hg[t];
    }
  }
}

// ------------- K8: scan pass 3 — re-scan with carry-in, emit y ---------------
// N-split like scan1; y = own-half dot + __shfl_xor partner half.
__global__ __launch_bounds__(256) void k_scan3(const float* __restrict__ x,
    const float* __restrict__ sel, const float* __restrict__ delta,
    const float* __restrict__ Bm, const float* __restrict__ Cm,
    const float* __restrict__ A_log, const float* __restrict__ hin,
    float* __restrict__ out) {
  int gid = blockIdx.x * 256 + threadIdx.x;   // 262144 threads
  int nh = gid & 1;
  int d = (gid >> 1) & (D_ - 1);
  int c = (gid >> 11) & (CCH - 1);
  int b = gid >> 17;
  float A[8], rA[8];
  unsigned smallm = 0;
  {
    const float4* ap = (const float4*)(A_log + d * N_ + nh * 8);
    float4 a0 = ap[0], a1 = ap[1];
    float av[8] = {a0.x, a0.y, a0.z, a0.w, a1.x, a1.y, a1.z, a1.w};
    #pragma unroll
    for (int n = 0; n < 8; ++n) {
      float a = -__expf(av[n]);
      A[n] = a; rA[n] = 1.f / a;
      if (fabsf(a) < 1e-6f) smallm |= (1u << n);
    }
  }
  float selv = sel[b * D_ + d];
  float h[8];
  {
    size_t base = ((size_t)(gid >> 1)) * N_ + nh * 8;
    const float4* hp = (const float4*)(hin + base);
    float4 v0 = hp[0], v1 = hp[1];
    h[0]=v0.x; h[1]=v0.y; h[2]=v0.z; h[3]=v0.w;
    h[4]=v1.x; h[5]=v1.y; h[6]=v1.z; h[7]=v1.w;
  }
  int row0 = b * L_ + c * TCH;
  #pragma unroll 4
  for (int s = 0; s < TCH; ++s) {
    int row = row0 + s;
    size_t idx = (size_t)row * D_ + d;
    float dlt = delta[idx];
    float xv = x[idx] * selv;
    const float4* bmp = (const float4*)(Bm + (size_t)row * N_ + nh * 8);
    float4 q0 = bmp[0], q1 = bmp[1];
    float bmv[8] = {q0.x, q0.y, q0.z, q0.w, q1.x, q1.y, q1.z, q1.w};
    const float4* cmp = (const float4*)(Cm + (size_t)row * N_ + nh * 8);
    float4 r0 = cmp[0], r1 = cmp[1];
    float cmv[8] = {r0.x, r0.y, r0.z, r0.w, r1.x, r1.y, r1.z, r1.w};
    float yp = 0.f;
    #pragma unroll
    for (int n = 0; n < 8; ++n) {
      float Ad = __expf(A[n] * dlt);
      float f = ((smallm >> n) & 1u) ? dlt : (Ad - 1.f) * rA[n];
      h[n] = Ad * h[n] + (f * bmv[n]) * xv;
      yp += h[n] * cmv[n];
    }
    float y = yp + __shfl_xor(yp, 1, 64);
    if (nh == 0) out[idx] = y;
  }
}

extern "C" void kernel_launch(void* const* d_in, const int* in_sizes, int n_in,
                              void* d_out, int out_size, void* d_ws, size_t ws_size,
                              hipStream_t stream) {
  const float* x       = (const float*)d_in[0];
  const float* deltaW  = (const float*)d_in[1];
  const float* deltab  = (const float*)d_in[2];
  const float* B_W     = (const float*)d_in[3];
  const float* B_b     = (const float*)d_in[4];
  const float* C_W     = (const float*)d_in[5];
  const float* C_b     = (const float*)d_in[6];
  const float* A_log   = (const float*)d_in[7];
  const float* dt_bias = (const float*)d_in[8];
  const float* tau     = (const float*)d_in[9];
  const float* Wi_W    = (const float*)d_in[10];
  const float* Wi_b    = (const float*)d_in[11];
  const float* Wr_W    = (const float*)d_in[12];
  const float* sel_W   = (const float*)d_in[13];
  const float* sel_b   = (const float*)d_in[14];
  const float* h0      = (const float*)d_in[15];
  float* out = (float*)d_out;

  float* ws    = (float*)d_ws;          // ~42.9 MB total
  float* delta = ws;                    // 4,194,304
  float* newh  = delta + 4194304;       // 64
  float* selp  = newh + 64;             // 2,048
  float* Bm    = selp + 2048;           // 65,536
  float* Cm    = Bm + 65536;            // 65,536
  float* prodA = Cm + 65536;            // 2,097,152  (aliases xb)
  float* hend  = prodA + 2097152;       // 2,097,152  (aliases Wp)
  float* hin   = hend + 2097152;        // 2,097,152  (aliases part1/part2)
  u16* xb    = (u16*)prodA;             // dead before scan1
  u16* Wp    = (u16*)hend;              // dead before scan1
  float* part1 = hin;                   // dead before scan2
  float* part2 = hin + 524288;          // dead before scan2

  hipLaunchKernelGGL(k_gc_pack, dim3(512), dim3(256), 0, stream, x, part1, xb);
  hipLaunchKernelGGL(k_gc_red, dim3(128), dim3(256), 0, stream, part1, part2);
  hipLaunchKernelGGL(k_newh, dim3(1), dim3(256), 0, stream,
                     part2, Wi_W, Wi_b, Wr_W, tau, h0, newh);
  hipLaunchKernelGGL(k_sel, dim3(8), dim3(256), 0, stream,
                     newh, sel_W, sel_b, selp);
  hipLaunchKernelGGL(k_pack_w, dim3(576, 2), dim3(256), 0, stream,
                     deltaW, B_W, C_W, selp, Wp);
  hipLaunchKernelGGL(k_gemm, dim3(32, 9), dim3(256), 0, stream,
                     xb, Wp, deltab, dt_bias, B_b, C_b, delta, Bm, Cm);
  hipLaunchKernelGGL(k_scan1, dim3(1024), dim3(256), 0, stream,
                     x, selp, delta, Bm, A_log, prodA, hend);
  hipLaunchKernelGGL(k_scan2, dim3(128), dim3(256), 0, stream,
                     prodA, hend, hin);
  hipLaunchKernelGGL(k_scan3, dim3(1024), dim3(256), 0, stream,
                     x, selp, delta, Bm, Cm, A_log, hin, out);
}

// Round 7
// 160.974 us; speedup vs baseline: 2.2072x; 1.3376x over previous
//
#include <hip/hip_runtime.h>
#include <hip/hip_bf16.h>
#include <math.h>

#define B_ 2
#define L_ 2048
#define D_ 1024
#define N_ 16
#define CCH 64   // chunks over L
#define TCH 32   // chunk length  (CCH*TCH == L_)
#define NCOLS 1056   // D_ + 2*N_
#define NPAD  1088   // 17 * 64

typedef unsigned short u16;
typedef __attribute__((ext_vector_type(8))) short short8v;
typedef __attribute__((ext_vector_type(8))) unsigned short ushort8v;
typedef __attribute__((ext_vector_type(4))) float f32x4;

__device__ __forceinline__ float softplusf(float z) {
  return fmaxf(z, 0.f) + log1pf(__expf(-fabsf(z)));
}

__device__ __forceinline__ u16 bf16rne(float f) {
  union { float f; unsigned u; } c; c.f = f;
  unsigned u = c.u;
  u += 0x7fffu + ((u >> 16) & 1u);
  return (u16)(u >> 16);
}

__device__ __forceinline__ void gl_lds16(const void* g, const u16* lds_base,
                                         int byte_off) {
  byte_off = __builtin_amdgcn_readfirstlane(byte_off);
  __builtin_amdgcn_global_load_lds(
      (const __attribute__((address_space(1))) void*)g,
      (__attribute__((address_space(3))) void*)((const char*)lds_base + byte_off),
      16, 0, 0);
}

// ------------- K1: fused gc partial-sum + x -> bf16 pack ---------------------
__global__ __launch_bounds__(256) void k_gc_pack(const float* __restrict__ x,
    float* __restrict__ part1, u16* __restrict__ xb) {
  int blk = blockIdx.x;
  int b = blk >> 8, lc = blk & 255;
  int tid = threadIdx.x;
  int r0 = b * L_ + lc * 8;
  float4 s = {0.f, 0.f, 0.f, 0.f};
  #pragma unroll
  for (int q = 0; q < 8; ++q) {
    size_t off = (size_t)(r0 + q) * D_ + tid * 4;
    float4 v = *(const float4*)(x + off);
    s.x += v.x; s.y += v.y; s.z += v.z; s.w += v.w;
    ushort4 r;
    r.x = bf16rne(v.x); r.y = bf16rne(v.y);
    r.z = bf16rne(v.z); r.w = bf16rne(v.w);
    *(ushort4*)(xb + off) = r;
  }
  *(float4*)(part1 + (size_t)blk * D_ + tid * 4) = s;
}

// ------------- K1b: reduce part1[512][1024] -> part2[2][16][1024] ------------
__global__ __launch_bounds__(256) void k_gc_red(const float* __restrict__ part1,
                                                float* __restrict__ part2) {
  int gid = blockIdx.x * 256 + threadIdx.x;   // 32768 = (b, jc, d)
  int d = gid & 1023;
  int jc = (gid >> 10) & 15;
  int b = gid >> 14;
  float s = 0.f;
  #pragma unroll
  for (int t = 0; t < 16; ++t)
    s += part1[(size_t)(b * 256 + jc * 16 + t) * D_ + d];
  part2[gid] = s;
}

// ------------- K2: gc -> liquid scaler -> new_h [B,N] ------------------------
__global__ __launch_bounds__(256) void k_newh(const float* __restrict__ part2,
    const float* __restrict__ Wi_W, const float* __restrict__ Wi_b,
    const float* __restrict__ Wr_W, const float* __restrict__ tau,
    const float* __restrict__ h0, float* __restrict__ newh) {
  __shared__ float gcs[B_ * D_];
  int tid = threadIdx.x;
  for (int idx = tid; idx < B_ * D_; idx += 256) {
    int b = idx >> 10, d = idx & (D_ - 1);
    float s = 0.f;
    #pragma unroll
    for (int lc = 0; lc < 16; ++lc)
      s += part2[(size_t)((b << 4) | lc) * D_ + d];
    gcs[idx] = s * (1.f / L_);
  }
  __syncthreads();
  if (tid < B_ * N_) {
    int b = tid >> 4, n = tid & 15;
    float inp = Wi_b[n];
    const float* g = gcs + b * D_;
    const float* w = Wi_W + n * D_;
    for (int d = 0; d < D_; d += 4) {
      float4 gv = *(const float4*)(g + d);
      float4 wv = *(const float4*)(w + d);
      inp += gv.x * wv.x + gv.y * wv.y + gv.z * wv.z + gv.w * wv.w;
    }
    float rec = 0.f;
    for (int m = 0; m < N_; ++m) rec += h0[m] * Wr_W[n * N_ + m];
    float th = tanhf(inp + rec);
    float tc = fminf(fmaxf(tau[n], 0.1f), 10.f);
    float cur = h0[n];
    newh[tid] = cur + 0.1f * ((th - cur) / tc);   // DT = 0.1
  }
}

// ------------- K3: sel[b,d] = sigmoid(new_h @ sel_W.T + sel_b) ---------------
__global__ __launch_bounds__(256) void k_sel(const float* __restrict__ newh,
    const float* __restrict__ sel_W, const float* __restrict__ sel_b,
    float* __restrict__ sel) {
  int gid = blockIdx.x * 256 + threadIdx.x;   // over B*D
  int b = gid >> 10, d = gid & (D_ - 1);
  const float* w = sel_W + d * N_;
  const float* h = newh + b * N_;
  float z = sel_b[d];
  #pragma unroll
  for (int n = 0; n < N_; n += 4) {
    float4 wv = *(const float4*)(w + n);
    z += h[n] * wv.x + h[n + 1] * wv.y + h[n + 2] * wv.z + h[n + 3] * wv.w;
  }
  sel[gid] = 1.f / (1.f + __expf(-z));
}

// ------------- K4: pack [delta_W; B_W; C_W] * sel(b) -> bf16 -----------------
__global__ __launch_bounds__(256) void k_pack_w(const float* __restrict__ dW,
    const float* __restrict__ B_W, const float* __restrict__ C_W,
    const float* __restrict__ sel, u16* __restrict__ Wp) {
  int gid = blockIdx.x * 256 + threadIdx.x;    // 139264 threads, 8 elems each
  int b = blockIdx.y;
  size_t e = (size_t)gid * 8;                  // < 1114112
  int nn = (int)(e >> 10);
  int k = (int)(e & 1023);
  ushort8v r;
  if (nn < NCOLS) {
    const float* src = (nn < 1024) ? dW + (size_t)nn * 1024
                     : (nn < 1040) ? B_W + (size_t)(nn - 1024) * 1024
                                   : C_W + (size_t)(nn - 1040) * 1024;
    float4 s0 = *(const float4*)(src + k);
    float4 s1 = *(const float4*)(src + k + 4);
    const float* sp = sel + b * D_ + k;
    float4 e0 = *(const float4*)sp;
    float4 e1 = *(const float4*)(sp + 4);
    r[0] = bf16rne(s0.x * e0.x); r[1] = bf16rne(s0.y * e0.y);
    r[2] = bf16rne(s0.z * e0.z); r[3] = bf16rne(s0.w * e0.w);
    r[4] = bf16rne(s1.x * e1.x); r[5] = bf16rne(s1.y * e1.y);
    r[6] = bf16rne(s1.z * e1.z); r[7] = bf16rne(s1.w * e1.w);
  } else {
    r = (ushort8v)0;
  }
  *(ushort8v*)(Wp + (size_t)b * (NPAD * 1024) + e) = r;
}

// ------------- K5: MFMA GEMM  C[4096 x 1088] = xb @ Wp^T ---------------------
// 64x64 tile, BK=64, 4 waves (2x2, wave-tile 32x32), double-buffered
// global_load_lds, counted vmcnt(4), XOR-swizzled source + swizzled ds_read.
// Grid 64x17 = 1088 blocks, 32 KB LDS -> ~4-5 blocks/CU for TLP.
__global__ __launch_bounds__(256) void k_gemm(
    const u16* __restrict__ xb, const u16* __restrict__ Wp,
    const float* __restrict__ delta_b, const float* __restrict__ dt_bias,
    const float* __restrict__ B_b, const float* __restrict__ C_b,
    float* __restrict__ delta, float* __restrict__ Bm, float* __restrict__ Cm) {
  __shared__ __align__(16) u16 lds[4][4096];   // At0,At1,Bt0,Bt1 (8 KB each)
  int m0 = blockIdx.x * 64;
  int n0 = blockIdx.y * 64;
  int batch = blockIdx.x >> 5;                 // 32 m-tiles per batch
  const u16* wb = Wp + (size_t)batch * (NPAD * 1024);
  int tid = threadIdx.x;
  int w = tid >> 6, l = tid & 63;
  int wr = w >> 1, wc = w & 1;
  int srow = l >> 3;
  int ssl = (l & 7) ^ srow;

  f32x4 acc[2][2];
  #pragma unroll
  for (int m = 0; m < 2; ++m)
    #pragma unroll
    for (int n = 0; n < 2; ++n)
      acc[m][n] = (f32x4){0.f, 0.f, 0.f, 0.f};

  // wave w stages rows [w*16, w*16+16) of A and B: 4 gl_lds per wave.
  #define STAGE(kb, buf)                                                       \
    {                                                                          \
      _Pragma("unroll")                                                        \
      for (int q = 0; q < 2; ++q) {                                            \
        int row = w * 16 + q * 8 + srow;                                       \
        gl_lds16(xb + (size_t)(m0 + row) * 1024 + (kb) * 64 + ssl * 8,         \
                 &lds[0][0], (buf) * 8192 + (w * 16 + q * 8) * 128);           \
        gl_lds16(wb + (size_t)(n0 + row) * 1024 + (kb) * 64 + ssl * 8,         \
                 &lds[0][0], 16384 + (buf) * 8192 + (w * 16 + q * 8) * 128);   \
      }                                                                        \
    }

  int lr = l & 15, lh = l >> 4;

  #define CSTEP(cur)                                                           \
    {                                                                          \
      _Pragma("unroll")                                                        \
      for (int ks = 0; ks < 2; ++ks) {                                         \
        short8v a[2], bq[2];                                                   \
        _Pragma("unroll")                                                      \
        for (int m = 0; m < 2; ++m) {                                          \
          int r = wr * 32 + m * 16 + lr;                                       \
          int ps = (ks * 4 + lh) ^ (r & 7);                                    \
          a[m] = *(const short8v*)((const char*)&lds[0][0] + (cur) * 8192 + r * 128 + ps * 16);\
        }                                                                      \
        _Pragma("unroll")                                                      \
        for (int n = 0; n < 2; ++n) {                                          \
          int r = wc * 32 + n * 16 + lr;                                       \
          int ps = (ks * 4 + lh) ^ (r & 7);                                    \
          bq[n] = *(const short8v*)((const char*)&lds[0][0] + 16384 + (cur) * 8192 + r * 128 + ps * 16);\
        }                                                                      \
        _Pragma("unroll")                                                      \
        for (int m = 0; m < 2; ++m)                                            \
          _Pragma("unroll")                                                    \
          for (int n = 0; n < 2; ++n)                                          \
            acc[m][n] = __builtin_amdgcn_mfma_f32_16x16x32_bf16(a[m], bq[n],   \
                                                                acc[m][n], 0, 0, 0);\
      }                                                                        \
    }

  STAGE(0, 0);
  STAGE(1, 1);
  #pragma unroll
  for (int kb = 0; kb < 15; ++kb) {
    int cur = kb & 1;
    asm volatile("s_waitcnt vmcnt(4)" ::: "memory");   // tile kb staged
    __builtin_amdgcn_s_barrier();
    CSTEP(cur);
    asm volatile("s_waitcnt lgkmcnt(0)" ::: "memory");
    __builtin_amdgcn_s_barrier();
    if (kb < 14) STAGE(kb + 2, cur);
  }
  asm volatile("s_waitcnt vmcnt(0)" ::: "memory");
  __builtin_amdgcn_s_barrier();
  CSTEP(1);
  #undef STAGE
  #undef CSTEP

  int ibase = m0 + wr * 32 + lh * 4;
  int jbase = n0 + wc * 32 + lr;
  #pragma unroll
  for (int m = 0; m < 2; ++m) {
    #pragma unroll
    for (int n = 0; n < 2; ++n) {
      int j = jbase + n * 16;
      #pragma unroll
      for (int r = 0; r < 2 * 2; ++r) {
        int i = ibase + m * 16 + r;
        float v = acc[m][n][r];
        if (j < 1024) {
          delta[(size_t)i * D_ + j] = softplusf(v + delta_b[j] + dt_bias[j]);
        } else if (j < 1040) {
          Bm[i * N_ + (j - 1024)] = v + B_b[j - 1024];
        } else if (j < NCOLS) {
          Cm[i * N_ + (j - 1040)] = v + C_b[j - 1040];
        }
      }
    }
  }
}

// ------------- K6: scan pass 1 — local scan + decay product ------------------
// N-split (8 states/thread) + ring-buffer prefetch: x/delta 4-deep, Bm 2-deep.
__global__ __launch_bounds__(256) void k_scan1(const float* __restrict__ x,
    const float* __restrict__ sel, const float* __restrict__ delta,
    const float* __restrict__ Bm, const float* __restrict__ A_log,
    float* __restrict__ prodA, float* __restrict__ hend) {
  int gid = blockIdx.x * 256 + threadIdx.x;   // ((b*CCH+c)*D + d)*2 + nh
  int nh = gid & 1;
  int d = (gid >> 1) & (D_ - 1);
  int c = (gid >> 11) & (CCH - 1);
  int b = gid >> 17;
  float A[8], rA[8];
  unsigned smallm = 0;
  {
    const float4* ap = (const float4*)(A_log + d * N_ + nh * 8);
    float4 a0 = ap[0], a1 = ap[1];
    float av[8] = {a0.x, a0.y, a0.z, a0.w, a1.x, a1.y, a1.z, a1.w};
    #pragma unroll
    for (int n = 0; n < 8; ++n) {
      float a = -__expf(av[n]);
      A[n] = a; rA[n] = 1.f / a;
      if (fabsf(a) < 1e-6f) smallm |= (1u << n);
    }
  }
  float selv = sel[b * D_ + d];
  int row0 = b * L_ + c * TCH;
  const float* xp = x + (size_t)row0 * D_ + d;
  const float* dp = delta + (size_t)row0 * D_ + d;
  const float4* bmp = (const float4*)(Bm + (size_t)row0 * N_) + nh * 2;
  float xs[4], dl[4];
  float4 b0[2], b1[2];
  #pragma unroll
  for (int s = 0; s < 4; ++s) { xs[s] = xp[(size_t)s * D_]; dl[s] = dp[(size_t)s * D_]; }
  #pragma unroll
  for (int s = 0; s < 2; ++s) { b0[s] = bmp[s * 4]; b1[s] = bmp[s * 4 + 1]; }
  float h[8], p[8];
  #pragma unroll
  for (int n = 0; n < 8; ++n) { h[n] = 0.f; p[n] = 1.f; }
  #pragma unroll
  for (int s = 0; s < TCH; ++s) {
    float dlt = dl[s & 3];
    float xv = xs[s & 3] * selv;
    float4 q0 = b0[s & 1], q1 = b1[s & 1];
    if (s + 4 < TCH) {
      xs[s & 3] = xp[(size_t)(s + 4) * D_];
      dl[s & 3] = dp[(size_t)(s + 4) * D_];
    }
    if (s + 2 < TCH) {
      b0[s & 1] = bmp[(s + 2) * 4];
      b1[s & 1] = bmp[(s + 2) * 4 + 1];
    }
    float bmv[8] = {q0.x, q0.y, q0.z, q0.w, q1.x, q1.y, q1.z, q1.w};
    #pragma unroll
    for (int n = 0; n < 8; ++n) {
      float Ad = __expf(A[n] * dlt);
      float f = ((smallm >> n) & 1u) ? dlt : (Ad - 1.f) * rA[n];
      h[n] = Ad * h[n] + (f * bmv[n]) * xv;
      p[n] *= Ad;
    }
  }
  size_t base = ((size_t)(gid >> 1)) * N_ + nh * 8;
  float4* pp = (float4*)(prodA + base);
  float4* hp = (float4*)(hend + base);
  pp[0] = make_float4(p[0], p[1], p[2], p[3]);
  pp[1] = make_float4(p[4], p[5], p[6], p[7]);
  hp[0] = make_float4(h[0], h[1], h[2], h[3]);
  hp[1] = make_float4(h[4], h[5], h[6], h[7]);
}

// ------------- K7: scan pass 2 — cross-chunk prefix (per b,d,n) --------------
__global__ __launch_bounds__(256) void k_scan2(const float* __restrict__ prodA,
    const float* __restrict__ hend, float* __restrict__ hin) {
  int gid = blockIdx.x * 256 + threadIdx.x;   // over B*D*N = 32768
  int b = gid >> 14;
  int rem = gid & 16383;
  size_t base = ((size_t)(b * CCH) << 14) + rem;
  float H = 0.f;
  #pragma unroll
  for (int g = 0; g < 4; ++g) {
    float pg[16], hg[16];
    #pragma unroll
    for (int t = 0; t < 16; ++t) {
      size_t idx = base + ((size_t)(g * 16 + t) << 14);
      pg[t] = prodA[idx];
      hg[t] = hend[idx];
    }
    #pragma unroll
    for (int t = 0; t < 16; ++t) {
      size_t idx = base + ((size_t)(g * 16 + t) << 14);
      hin[idx] = H;
      H = pg[t] * H + hg[t];
    }
  }
}

// ------------- K8: scan pass 3 — re-scan with carry-in, emit y ---------------
// N-split + ring prefetch (x/delta 4-deep, Bm/Cm 2-deep); shfl_xor y-reduce.
__global__ __launch_bounds__(256) void k_scan3(const float* __restrict__ x,
    const float* __restrict__ sel, const float* __restrict__ delta,
    const float* __restrict__ Bm, const float* __restrict__ Cm,
    const float* __restrict__ A_log, const float* __restrict__ hin,
    float* __restrict__ out) {
  int gid = blockIdx.x * 256 + threadIdx.x;   // 262144 threads
  int nh = gid & 1;
  int d = (gid >> 1) & (D_ - 1);
  int c = (gid >> 11) & (CCH - 1);
  int b = gid >> 17;
  float A[8], rA[8];
  unsigned smallm = 0;
  {
    const float4* ap = (const float4*)(A_log + d * N_ + nh * 8);
    float4 a0 = ap[0], a1 = ap[1];
    float av[8] = {a0.x, a0.y, a0.z, a0.w, a1.x, a1.y, a1.z, a1.w};
    #pragma unroll
    for (int n = 0; n < 8; ++n) {
      float a = -__expf(av[n]);
      A[n] = a; rA[n] = 1.f / a;
      if (fabsf(a) < 1e-6f) smallm |= (1u << n);
    }
  }
  float selv = sel[b * D_ + d];
  float h[8];
  {
    size_t base = ((size_t)(gid >> 1)) * N_ + nh * 8;
    const float4* hp = (const float4*)(hin + base);
    float4 v0 = hp[0], v1 = hp[1];
    h[0]=v0.x; h[1]=v0.y; h[2]=v0.z; h[3]=v0.w;
    h[4]=v1.x; h[5]=v1.y; h[6]=v1.z; h[7]=v1.w;
  }
  int row0 = b * L_ + c * TCH;
  const float* xp = x + (size_t)row0 * D_ + d;
  const float* dp = delta + (size_t)row0 * D_ + d;
  const float4* bmp = (const float4*)(Bm + (size_t)row0 * N_) + nh * 2;
  const float4* cmp = (const float4*)(Cm + (size_t)row0 * N_) + nh * 2;
  float xs[4], dl[4];
  float4 b0[2], b1[2], c0[2], c1[2];
  #pragma unroll
  for (int s = 0; s < 4; ++s) { xs[s] = xp[(size_t)s * D_]; dl[s] = dp[(size_t)s * D_]; }
  #pragma unroll
  for (int s = 0; s < 2; ++s) {
    b0[s] = bmp[s * 4]; b1[s] = bmp[s * 4 + 1];
    c0[s] = cmp[s * 4]; c1[s] = cmp[s * 4 + 1];
  }
  #pragma unroll
  for (int s = 0; s < TCH; ++s) {
    float dlt = dl[s & 3];
    float xv = xs[s & 3] * selv;
    float4 q0 = b0[s & 1], q1 = b1[s & 1];
    float4 r0 = c0[s & 1], r1 = c1[s & 1];
    if (s + 4 < TCH) {
      xs[s & 3] = xp[(size_t)(s + 4) * D_];
      dl[s & 3] = dp[(size_t)(s + 4) * D_];
    }
    if (s + 2 < TCH) {
      b0[s & 1] = bmp[(s + 2) * 4];
      b1[s & 1] = bmp[(s + 2) * 4 + 1];
      c0[s & 1] = cmp[(s + 2) * 4];
      c1[s & 1] = cmp[(s + 2) * 4 + 1];
    }
    float bmv[8] = {q0.x, q0.y, q0.z, q0.w, q1.x, q1.y, q1.z, q1.w};
    float cmv[8] = {r0.x, r0.y, r0.z, r0.w, r1.x, r1.y, r1.z, r1.w};
    float yp = 0.f;
    #pragma unroll
    for (int n = 0; n < 8; ++n) {
      float Ad = __expf(A[n] * dlt);
      float f = ((smallm >> n) & 1u) ? dlt : (Ad - 1.f) * rA[n];
      h[n] = Ad * h[n] + (f * bmv[n]) * xv;
      yp += h[n] * cmv[n];
    }
    float y = yp + __shfl_xor(yp, 1, 64);
    if (nh == 0) out[(size_t)(row0 + s) * D_ + d] = y;
  }
}

extern "C" void kernel_launch(void* const* d_in, const int* in_sizes, int n_in,
                              void* d_out, int out_size, void* d_ws, size_t ws_size,
                              hipStream_t stream) {
  const float* x       = (const float*)d_in[0];
  const float* deltaW  = (const float*)d_in[1];
  const float* deltab  = (const float*)d_in[2];
  const float* B_W     = (const float*)d_in[3];
  const float* B_b     = (const float*)d_in[4];
  const float* C_W     = (const float*)d_in[5];
  const float* C_b     = (const float*)d_in[6];
  const float* A_log   = (const float*)d_in[7];
  const float* dt_bias = (const float*)d_in[8];
  const float* tau     = (const float*)d_in[9];
  const float* Wi_W    = (const float*)d_in[10];
  const float* Wi_b    = (const float*)d_in[11];
  const float* Wr_W    = (const float*)d_in[12];
  const float* sel_W   = (const float*)d_in[13];
  const float* sel_b   = (const float*)d_in[14];
  const float* h0      = (const float*)d_in[15];
  float* out = (float*)d_out;

  float* ws    = (float*)d_ws;          // ~42.7 MB total
  float* delta = ws;                    // 4,194,304
  float* newh  = delta + 4194304;       // 64
  float* selp  = newh + 64;             // 2,048
  float* Bm    = selp + 2048;           // 65,536
  float* Cm    = Bm + 65536;            // 65,536
  float* prodA = Cm + 65536;            // 2,097,152  (aliases xb)
  float* hend  = prodA + 2097152;       // 2,097,152  (aliases Wp)
  float* hin   = hend + 2097152;        // 2,097,152  (aliases part1/part2)
  u16* xb    = (u16*)prodA;             // dead before scan1
  u16* Wp    = (u16*)hend;              // dead before scan1
  float* part1 = hin;                   // dead before scan2
  float* part2 = hin + 524288;          // dead before scan2

  hipLaunchKernelGGL(k_gc_pack, dim3(512), dim3(256), 0, stream, x, part1, xb);
  hipLaunchKernelGGL(k_gc_red, dim3(128), dim3(256), 0, stream, part1, part2);
  hipLaunchKernelGGL(k_newh, dim3(1), dim3(256), 0, stream,
                     part2, Wi_W, Wi_b, Wr_W, tau, h0, newh);
  hipLaunchKernelGGL(k_sel, dim3(8), dim3(256), 0, stream,
                     newh, sel_W, sel_b, selp);
  hipLaunchKernelGGL(k_pack_w, dim3(544, 2), dim3(256), 0, stream,
                     deltaW, B_W, C_W, selp, Wp);
  hipLaunchKernelGGL(k_gemm, dim3(64, 17), dim3(256), 0, stream,
                     xb, Wp, deltab, dt_bias, B_b, C_b, delta, Bm, Cm);
  hipLaunchKernelGGL(k_scan1, dim3(1024), dim3(256), 0, stream,
                     x, selp, delta, Bm, A_log, prodA, hend);
  hipLaunchKernelGGL(k_scan2, dim3(128), dim3(256), 0, stream,
                     prodA, hend, hin);
  hipLaunchKernelGGL(k_scan3, dim3(1024), dim3(256), 0, stream,
                     x, selp, delta, Bm, Cm, A_log, hin, out);
}

// Round 8
// 130.005 us; speedup vs baseline: 2.7330x; 1.2382x over previous
//
#include <hip/hip_runtime.h>
#include <hip/hip_bf16.h>
#include <math.h>

#define B_ 2
#define L_ 2048
#define D_ 1024
#define N_ 16
#define CCH 64   // chunks over L
#define TCH 32   // chunk length  (CCH*TCH == L_)
#define NCOLS 1056   // D_ + 2*N_
#define NPAD  1088   // 17 * 64

typedef unsigned short u16;
typedef __attribute__((ext_vector_type(8))) short short8v;
typedef __attribute__((ext_vector_type(8))) unsigned short ushort8v;
typedef __attribute__((ext_vector_type(4))) float f32x4;

__device__ __forceinline__ float softplusf(float z) {
  return fmaxf(z, 0.f) + log1pf(__expf(-fabsf(z)));
}

__device__ __forceinline__ u16 bf16rne(float f) {
  union { float f; unsigned u; } c; c.f = f;
  unsigned u = c.u;
  u += 0x7fffu + ((u >> 16) & 1u);
  return (u16)(u >> 16);
}

__device__ __forceinline__ void gl_lds16(const void* g, const u16* lds_base,
                                         int byte_off) {
  byte_off = __builtin_amdgcn_readfirstlane(byte_off);
  __builtin_amdgcn_global_load_lds(
      (const __attribute__((address_space(1))) void*)g,
      (__attribute__((address_space(3))) void*)((const char*)lds_base + byte_off),
      16, 0, 0);
}

// ------------- K1: fused gc partial-sum + x -> bf16 pack ---------------------
__global__ __launch_bounds__(256) void k_gc_pack(const float* __restrict__ x,
    float* __restrict__ part1, u16* __restrict__ xb) {
  int blk = blockIdx.x;
  int b = blk >> 8, lc = blk & 255;
  int tid = threadIdx.x;
  int r0 = b * L_ + lc * 8;
  float4 s = {0.f, 0.f, 0.f, 0.f};
  #pragma unroll
  for (int q = 0; q < 8; ++q) {
    size_t off = (size_t)(r0 + q) * D_ + tid * 4;
    float4 v = *(const float4*)(x + off);
    s.x += v.x; s.y += v.y; s.z += v.z; s.w += v.w;
    ushort4 r;
    r.x = bf16rne(v.x); r.y = bf16rne(v.y);
    r.z = bf16rne(v.z); r.w = bf16rne(v.w);
    *(ushort4*)(xb + off) = r;
  }
  *(float4*)(part1 + (size_t)blk * D_ + tid * 4) = s;
}

// ------------- K1b: reduce part1[512][1024] -> part2[2][16][1024] ------------
__global__ __launch_bounds__(256) void k_gc_red(const float* __restrict__ part1,
                                                float* __restrict__ part2) {
  int gid = blockIdx.x * 256 + threadIdx.x;   // 32768 = (b, jc, d)
  int d = gid & 1023;
  int jc = (gid >> 10) & 15;
  int b = gid >> 14;
  float s = 0.f;
  #pragma unroll
  for (int t = 0; t < 16; ++t)
    s += part1[(size_t)(b * 256 + jc * 16 + t) * D_ + d];
  part2[gid] = s;
}

// ------------- K2: gc -> liquid scaler -> new_h [B,N] ------------------------
__global__ __launch_bounds__(256) void k_newh(const float* __restrict__ part2,
    const float* __restrict__ Wi_W, const float* __restrict__ Wi_b,
    const float* __restrict__ Wr_W, const float* __restrict__ tau,
    const float* __restrict__ h0, float* __restrict__ newh) {
  __shared__ float gcs[B_ * D_];
  int tid = threadIdx.x;
  for (int idx = tid; idx < B_ * D_; idx += 256) {
    int b = idx >> 10, d = idx & (D_ - 1);
    float s = 0.f;
    #pragma unroll
    for (int lc = 0; lc < 16; ++lc)
      s += part2[(size_t)((b << 4) | lc) * D_ + d];
    gcs[idx] = s * (1.f / L_);
  }
  __syncthreads();
  if (tid < B_ * N_) {
    int b = tid >> 4, n = tid & 15;
    float inp = Wi_b[n];
    const float* g = gcs + b * D_;
    const float* w = Wi_W + n * D_;
    for (int d = 0; d < D_; d += 4) {
      float4 gv = *(const float4*)(g + d);
      float4 wv = *(const float4*)(w + d);
      inp += gv.x * wv.x + gv.y * wv.y + gv.z * wv.z + gv.w * wv.w;
    }
    float rec = 0.f;
    for (int m = 0; m < N_; ++m) rec += h0[m] * Wr_W[n * N_ + m];
    float th = tanhf(inp + rec);
    float tc = fminf(fmaxf(tau[n], 0.1f), 10.f);
    float cur = h0[n];
    newh[tid] = cur + 0.1f * ((th - cur) / tc);   // DT = 0.1
  }
}

// ------------- K3: sel[b,d] = sigmoid(new_h @ sel_W.T + sel_b) ---------------
__global__ __launch_bounds__(256) void k_sel(const float* __restrict__ newh,
    const float* __restrict__ sel_W, const float* __restrict__ sel_b,
    float* __restrict__ sel) {
  int gid = blockIdx.x * 256 + threadIdx.x;   // over B*D
  int b = gid >> 10, d = gid & (D_ - 1);
  const float* w = sel_W + d * N_;
  const float* h = newh + b * N_;
  float z = sel_b[d];
  #pragma unroll
  for (int n = 0; n < N_; n += 4) {
    float4 wv = *(const float4*)(w + n);
    z += h[n] * wv.x + h[n + 1] * wv.y + h[n + 2] * wv.z + h[n + 3] * wv.w;
  }
  sel[gid] = 1.f / (1.f + __expf(-z));
}

// ------------- K4: pack [delta_W; B_W; C_W] * sel(b) -> bf16 -----------------
__global__ __launch_bounds__(256) void k_pack_w(const float* __restrict__ dW,
    const float* __restrict__ B_W, const float* __restrict__ C_W,
    const float* __restrict__ sel, u16* __restrict__ Wp) {
  int gid = blockIdx.x * 256 + threadIdx.x;    // 139264 threads, 8 elems each
  int b = blockIdx.y;
  size_t e = (size_t)gid * 8;                  // < 1114112
  int nn = (int)(e >> 10);
  int k = (int)(e & 1023);
  ushort8v r;
  if (nn < NCOLS) {
    const float* src = (nn < 1024) ? dW + (size_t)nn * 1024
                     : (nn < 1040) ? B_W + (size_t)(nn - 1024) * 1024
                                   : C_W + (size_t)(nn - 1040) * 1024;
    float4 s0 = *(const float4*)(src + k);
    float4 s1 = *(const float4*)(src + k + 4);
    const float* sp = sel + b * D_ + k;
    float4 e0 = *(const float4*)sp;
    float4 e1 = *(const float4*)(sp + 4);
    r[0] = bf16rne(s0.x * e0.x); r[1] = bf16rne(s0.y * e0.y);
    r[2] = bf16rne(s0.z * e0.z); r[3] = bf16rne(s0.w * e0.w);
    r[4] = bf16rne(s1.x * e1.x); r[5] = bf16rne(s1.y * e1.y);
    r[6] = bf16rne(s1.z * e1.z); r[7] = bf16rne(s1.w * e1.w);
  } else {
    r = (ushort8v)0;
  }
  *(ushort8v*)(Wp + (size_t)b * (NPAD * 1024) + e) = r;
}

// ------------- K5: MFMA GEMM  C[4096 x 1088] = xb @ Wp^T ---------------------
// 64x64 tile, BK=64, counted vmcnt(4) double-buffer, XOR swizzle. 1088 blocks.
__global__ __launch_bounds__(256) void k_gemm(
    const u16* __restrict__ xb, const u16* __restrict__ Wp,
    const float* __restrict__ delta_b, const float* __restrict__ dt_bias,
    const float* __restrict__ B_b, const float* __restrict__ C_b,
    float* __restrict__ delta, float* __restrict__ Bm, float* __restrict__ Cm) {
  __shared__ __align__(16) u16 lds[4][4096];   // At0,At1,Bt0,Bt1 (8 KB each)
  int m0 = blockIdx.x * 64;
  int n0 = blockIdx.y * 64;
  int batch = blockIdx.x >> 5;                 // 32 m-tiles per batch
  const u16* wb = Wp + (size_t)batch * (NPAD * 1024);
  int tid = threadIdx.x;
  int w = tid >> 6, l = tid & 63;
  int wr = w >> 1, wc = w & 1;
  int srow = l >> 3;
  int ssl = (l & 7) ^ srow;

  f32x4 acc[2][2];
  #pragma unroll
  for (int m = 0; m < 2; ++m)
    #pragma unroll
    for (int n = 0; n < 2; ++n)
      acc[m][n] = (f32x4){0.f, 0.f, 0.f, 0.f};

  #define STAGE(kb, buf)                                                       \
    {                                                                          \
      _Pragma("unroll")                                                        \
      for (int q = 0; q < 2; ++q) {                                            \
        int row = w * 16 + q * 8 + srow;                                       \
        gl_lds16(xb + (size_t)(m0 + row) * 1024 + (kb) * 64 + ssl * 8,         \
                 &lds[0][0], (buf) * 8192 + (w * 16 + q * 8) * 128);           \
        gl_lds16(wb + (size_t)(n0 + row) * 1024 + (kb) * 64 + ssl * 8,         \
                 &lds[0][0], 16384 + (buf) * 8192 + (w * 16 + q * 8) * 128);   \
      }                                                                        \
    }

  int lr = l & 15, lh = l >> 4;

  #define CSTEP(cur)                                                           \
    {                                                                          \
      _Pragma("unroll")                                                        \
      for (int ks = 0; ks < 2; ++ks) {                                         \
        short8v a[2], bq[2];                                                   \
        _Pragma("unroll")                                                      \
        for (int m = 0; m < 2; ++m) {                                          \
          int r = wr * 32 + m * 16 + lr;                                       \
          int ps = (ks * 4 + lh) ^ (r & 7);                                    \
          a[m] = *(const short8v*)((const char*)&lds[0][0] + (cur) * 8192 + r * 128 + ps * 16);\
        }                                                                      \
        _Pragma("unroll")                                                      \
        for (int n = 0; n < 2; ++n) {                                          \
          int r = wc * 32 + n * 16 + lr;                                       \
          int ps = (ks * 4 + lh) ^ (r & 7);                                    \
          bq[n] = *(const short8v*)((const char*)&lds[0][0] + 16384 + (cur) * 8192 + r * 128 + ps * 16);\
        }                                                                      \
        _Pragma("unroll")                                                      \
        for (int m = 0; m < 2; ++m)                                            \
          _Pragma("unroll")                                                    \
          for (int n = 0; n < 2; ++n)                                          \
            acc[m][n] = __builtin_amdgcn_mfma_f32_16x16x32_bf16(a[m], bq[n],   \
                                                                acc[m][n], 0, 0, 0);\
      }                                                                        \
    }

  STAGE(0, 0);
  STAGE(1, 1);
  #pragma unroll
  for (int kb = 0; kb < 15; ++kb) {
    int cur = kb & 1;
    asm volatile("s_waitcnt vmcnt(4)" ::: "memory");   // tile kb staged
    __builtin_amdgcn_s_barrier();
    CSTEP(cur);
    asm volatile("s_waitcnt lgkmcnt(0)" ::: "memory");
    __builtin_amdgcn_s_barrier();
    if (kb < 14) STAGE(kb + 2, cur);
  }
  asm volatile("s_waitcnt vmcnt(0)" ::: "memory");
  __builtin_amdgcn_s_barrier();
  CSTEP(1);
  #undef STAGE
  #undef CSTEP

  int ibase = m0 + wr * 32 + lh * 4;
  int jbase = n0 + wc * 32 + lr;
  #pragma unroll
  for (int m = 0; m < 2; ++m) {
    #pragma unroll
    for (int n = 0; n < 2; ++n) {
      int j = jbase + n * 16;
      #pragma unroll
      for (int r = 0; r < 2 * 2; ++r) {
        int i = ibase + m * 16 + r;
        float v = acc[m][n][r];
        if (j < 1024) {
          delta[(size_t)i * D_ + j] = softplusf(v + delta_b[j] + dt_bias[j]);
        } else if (j < 1040) {
          Bm[i * N_ + (j - 1024)] = v + B_b[j - 1024];
        } else if (j < NCOLS) {
          Cm[i * N_ + (j - 1040)] = v + C_b[j - 1040];
        }
      }
    }
  }
}

// ------------- K6: scan pass 1 — local scan + decay product ------------------
// 4-way N-split: thread = (b,c,d,nq), 4 states each. 2048 blocks, streaming.
__global__ __launch_bounds__(256) void k_scan1(const float* __restrict__ x,
    const float* __restrict__ sel, const float* __restrict__ delta,
    const float* __restrict__ Bm, const float* __restrict__ A_log,
    float* __restrict__ prodA, float* __restrict__ hend) {
  int gid = blockIdx.x * 256 + threadIdx.x;   // ((b*CCH+c)*D + d)*4 + nq
  int nq = gid & 3;
  int d = (gid >> 2) & (D_ - 1);
  int c = (gid >> 12) & (CCH - 1);
  int b = gid >> 18;
  float A[4], rA[4];
  unsigned smallm = 0;
  {
    float4 a0 = *(const float4*)(A_log + d * N_ + nq * 4);
    float av[4] = {a0.x, a0.y, a0.z, a0.w};
    #pragma unroll
    for (int n = 0; n < 4; ++n) {
      float a = -__expf(av[n]);
      A[n] = a; rA[n] = 1.f / a;
      if (fabsf(a) < 1e-6f) smallm |= (1u << n);
    }
  }
  float selv = sel[b * D_ + d];
  float h[4], p[4];
  #pragma unroll
  for (int n = 0; n < 4; ++n) { h[n] = 0.f; p[n] = 1.f; }
  int row0 = b * L_ + c * TCH;
  const float* xp = x + (size_t)row0 * D_ + d;
  const float* dp = delta + (size_t)row0 * D_ + d;
  const float4* bmp = (const float4*)(Bm + (size_t)row0 * N_) + nq;
  #pragma unroll 4
  for (int s = 0; s < TCH; ++s) {
    float dlt = dp[(size_t)s * D_];
    float xv = xp[(size_t)s * D_] * selv;
    float4 q0 = bmp[s * 4];
    float bmv[4] = {q0.x, q0.y, q0.z, q0.w};
    #pragma unroll
    for (int n = 0; n < 4; ++n) {
      float Ad = __expf(A[n] * dlt);
      float f = ((smallm >> n) & 1u) ? dlt : (Ad - 1.f) * rA[n];
      h[n] = Ad * h[n] + (f * bmv[n]) * xv;
      p[n] *= Ad;
    }
  }
  size_t base = ((size_t)(gid >> 2)) * N_ + nq * 4;
  *(float4*)(prodA + base) = make_float4(p[0], p[1], p[2], p[3]);
  *(float4*)(hend + base)  = make_float4(h[0], h[1], h[2], h[3]);
}

// ------------- K7: scan pass 2 — cross-chunk prefix (per b,d,n) --------------
__global__ __launch_bounds__(256) void k_scan2(const float* __restrict__ prodA,
    const float* __restrict__ hend, float* __restrict__ hin) {
  int gid = blockIdx.x * 256 + threadIdx.x;   // over B*D*N = 32768
  int b = gid >> 14;
  int rem = gid & 16383;
  size_t base = ((size_t)(b * CCH) << 14) + rem;
  float H = 0.f;
  #pragma unroll
  for (int g = 0; g < 4; ++g) {
    float pg[16], hg[16];
    #pragma unroll
    for (int t = 0; t < 16; ++t) {
      size_t idx = base + ((size_t)(g * 16 + t) << 14);
      pg[t] = prodA[idx];
      hg[t] = hend[idx];
    }
    #pragma unroll
    for (int t = 0; t < 16; ++t) {
      size_t idx = base + ((size_t)(g * 16 + t) << 14);
      hin[idx] = H;
      H = pg[t] * H + hg[t];
    }
  }
}

// ------------- K8: scan pass 3 — re-scan with carry-in, emit y ---------------
// 4-way N-split; y reduced over the lane quad via shfl_xor(1), shfl_xor(2).
__global__ __launch_bounds__(256) void k_scan3(const float* __restrict__ x,
    const float* __restrict__ sel, const float* __restrict__ delta,
    const float* __restrict__ Bm, const float* __restrict__ Cm,
    const float* __restrict__ A_log, const float* __restrict__ hin,
    float* __restrict__ out) {
  int gid = blockIdx.x * 256 + threadIdx.x;   // 524288 threads
  int nq = gid & 3;
  int d = (gid >> 2) & (D_ - 1);
  int c = (gid >> 12) & (CCH - 1);
  int b = gid >> 18;
  float A[4], rA[4];
  unsigned smallm = 0;
  {
    float4 a0 = *(const float4*)(A_log + d * N_ + nq * 4);
    float av[4] = {a0.x, a0.y, a0.z, a0.w};
    #pragma unroll
    for (int n = 0; n < 4; ++n) {
      float a = -__expf(av[n]);
      A[n] = a; rA[n] = 1.f / a;
      if (fabsf(a) < 1e-6f) smallm |= (1u << n);
    }
  }
  float selv = sel[b * D_ + d];
  float h[4];
  {
    size_t base = ((size_t)(gid >> 2)) * N_ + nq * 4;
    float4 v0 = *(const float4*)(hin + base);
    h[0] = v0.x; h[1] = v0.y; h[2] = v0.z; h[3] = v0.w;
  }
  int row0 = b * L_ + c * TCH;
  const float* xp = x + (size_t)row0 * D_ + d;
  const float* dp = delta + (size_t)row0 * D_ + d;
  const float4* bmp = (const float4*)(Bm + (size_t)row0 * N_) + nq;
  const float4* cmp = (const float4*)(Cm + (size_t)row0 * N_) + nq;
  float* op = out + (size_t)row0 * D_ + d;
  #pragma unroll 4
  for (int s = 0; s < TCH; ++s) {
    float dlt = dp[(size_t)s * D_];
    float xv = xp[(size_t)s * D_] * selv;
    float4 q0 = bmp[s * 4];
    float4 r0 = cmp[s * 4];
    float bmv[4] = {q0.x, q0.y, q0.z, q0.w};
    float cmv[4] = {r0.x, r0.y, r0.z, r0.w};
    float yp = 0.f;
    #pragma unroll
    for (int n = 0; n < 4; ++n) {
      float Ad = __expf(A[n] * dlt);
      float f = ((smallm >> n) & 1u) ? dlt : (Ad - 1.f) * rA[n];
      h[n] = Ad * h[n] + (f * bmv[n]) * xv;
      yp += h[n] * cmv[n];
    }
    float y = yp + __shfl_xor(yp, 1, 64);
    y += __shfl_xor(y, 2, 64);
    if (nq == 0) op[(size_t)s * D_] = y;
  }
}

extern "C" void kernel_launch(void* const* d_in, const int* in_sizes, int n_in,
                              void* d_out, int out_size, void* d_ws, size_t ws_size,
                              hipStream_t stream) {
  const float* x       = (const float*)d_in[0];
  const float* deltaW  = (const float*)d_in[1];
  const float* deltab  = (const float*)d_in[2];
  const float* B_W     = (const float*)d_in[3];
  const float* B_b     = (const float*)d_in[4];
  const float* C_W     = (const float*)d_in[5];
  const float* C_b     = (const float*)d_in[6];
  const float* A_log   = (const float*)d_in[7];
  const float* dt_bias = (const float*)d_in[8];
  const float* tau     = (const float*)d_in[9];
  const float* Wi_W    = (const float*)d_in[10];
  const float* Wi_b    = (const float*)d_in[11];
  const float* Wr_W    = (const float*)d_in[12];
  const float* sel_W   = (const float*)d_in[13];
  const float* sel_b   = (const float*)d_in[14];
  const float* h0      = (const float*)d_in[15];
  float* out = (float*)d_out;

  float* ws    = (float*)d_ws;          // ~42.7 MB total
  float* delta = ws;                    // 4,194,304
  float* newh  = delta + 4194304;       // 64
  float* selp  = newh + 64;             // 2,048
  float* Bm    = selp + 2048;           // 65,536
  float* Cm    = Bm + 65536;            // 65,536
  float* prodA = Cm + 65536;            // 2,097,152  (aliases xb)
  float* hend  = prodA + 2097152;       // 2,097,152  (aliases Wp)
  float* hin   = hend + 2097152;        // 2,097,152  (aliases part1/part2)
  u16* xb    = (u16*)prodA;             // dead before scan1
  u16* Wp    = (u16*)hend;              // dead before scan1
  float* part1 = hin;                   // dead before scan2
  float* part2 = hin + 524288;          // dead before scan2

  hipLaunchKernelGGL(k_gc_pack, dim3(512), dim3(256), 0, stream, x, part1, xb);
  hipLaunchKernelGGL(k_gc_red, dim3(128), dim3(256), 0, stream, part1, part2);
  hipLaunchKernelGGL(k_newh, dim3(1), dim3(256), 0, stream,
                     part2, Wi_W, Wi_b, Wr_W, tau, h0, newh);
  hipLaunchKernelGGL(k_sel, dim3(8), dim3(256), 0, stream,
                     newh, sel_W, sel_b, selp);
  hipLaunchKernelGGL(k_pack_w, dim3(544, 2), dim3(256), 0, stream,
                     deltaW, B_W, C_W, selp, Wp);
  hipLaunchKernelGGL(k_gemm, dim3(64, 17), dim3(256), 0, stream,
                     xb, Wp, deltab, dt_bias, B_b, C_b, delta, Bm, Cm);
  hipLaunchKernelGGL(k_scan1, dim3(2048), dim3(256), 0, stream,
                     x, selp, delta, Bm, A_log, prodA, hend);
  hipLaunchKernelGGL(k_scan2, dim3(128), dim3(256), 0, stream,
                     prodA, hend, hin);
  hipLaunchKernelGGL(k_scan3, dim3(2048), dim3(256), 0, stream,
                     x, selp, delta, Bm, Cm, A_log, hin, out);
}